// Round 9
// baseline (14463.744 us; speedup 1.0000x reference)
//
#include <hip/hip_runtime.h>
#include <math.h>

#define HID    512
#define NIN    256
#define TIN    4096
#define NSTEP  1023
#define NEVAL  (NSTEP*4)
#define NWG    16
#define SLICE  32
#define NTH    1024
#define NLAUNCH 128

// ---------- agent-scope helpers (LLC point; PROVEN, rounds 2-8) ----------
__device__ __forceinline__ unsigned ag_load(const unsigned* p) {
  return __hip_atomic_load(p, __ATOMIC_RELAXED, __HIP_MEMORY_SCOPE_AGENT);
}
__device__ __forceinline__ void ag_store(unsigned* p, unsigned v) {
  __hip_atomic_store(p, v, __ATOMIC_RELAXED, __HIP_MEMORY_SCOPE_AGENT);
}
__device__ __forceinline__ unsigned ag_add(unsigned* p, unsigned v) {
  return __hip_atomic_fetch_add(p, v, __ATOMIC_RELAXED, __HIP_MEMORY_SCOPE_AGENT);
}
__device__ __forceinline__ void ag_cas(unsigned* p, unsigned c, unsigned v) {
  unsigned e = c;
  __hip_atomic_compare_exchange_strong(p, &e, v, __ATOMIC_RELAXED, __ATOMIC_RELAXED,
                                       __HIP_MEMORY_SCOPE_AGENT);
}

// ---------- FAST-mode primitives ----------
// release: atomic swap, no sc flags -> executes at the XCD's L2 (r7-PROVEN visible)
__device__ __forceinline__ void l2_swap64(unsigned long long* p, unsigned long long v) {
  asm volatile("global_atomic_swap_x2 %0, %1, off" :: "v"(p), "v"(v) : "memory");
}
__device__ __forceinline__ void l2_swap32(unsigned* p, unsigned v) {
  asm volatile("global_atomic_swap %0, %1, off" :: "v"(p), "v"(v) : "memory");
}
// poll: plain sc0 load -> L1-bypass, served by the XCD L2; clean line (no writeback)
__device__ __forceinline__ unsigned long long sc0_load64(const unsigned long long* p) {
  unsigned long long v;
  asm volatile("global_load_dwordx2 %0, %1, off sc0\n\ts_waitcnt vmcnt(0)"
               : "=v"(v) : "v"(p) : "memory");
  return v;
}
__device__ __forceinline__ unsigned sc0_load32(const unsigned* p) {
  unsigned v;
  asm volatile("global_load_dword %0, %1, off sc0\n\ts_waitcnt vmcnt(0)"
               : "=v"(v) : "v"(p) : "memory");
  return v;
}

// searchsorted(linspace(0,1,4096), t, side='left') clipped to [0, 4095]
__device__ __forceinline__ int zoh_index(float t) {
  const float delta = 1.0f / 4095.0f;
  int lo = 0, hi = TIN;
  while (lo < hi) {
    int mid = (lo + hi) >> 1;
    float g = (float)mid * delta;
    if (g < t) lo = mid + 1; else hi = mid;
  }
  return lo > TIN - 1 ? TIN - 1 : lo;
}

// Round-3-proven gu precompute: gu[e][0:512]=U_tau@I+b_tau, gu[e][512:1024]=U_f@I+b_f
__global__ void __launch_bounds__(256)
gu_kernel(const float* __restrict__ I_seq, const float* __restrict__ t_save,
          const float* __restrict__ U_tau, const float* __restrict__ b_tau,
          const float* __restrict__ U_f,   const float* __restrict__ b_f,
          float* __restrict__ gu)
{
  __shared__ float Ish[NIN];
  const int e = blockIdx.x;
  const int tid = threadIdx.x;
  const int n = e >> 2, s = e & 3;
  const float t0 = t_save[n], t1 = t_save[n + 1];
  const float dt = t1 - t0;
  const float third = 1.0f / 3.0f;
  float t;
  if      (s == 0) t = t0;
  else if (s == 1) t = t0 + dt * third;
  else if (s == 2) t = t0 + (dt * 2.0f) * third;
  else             t = t1;
  const int idx = zoh_index(t);
  Ish[tid] = I_seq[idx * NIN + tid];
  __syncthreads();
  float* go = gu + (size_t)e * 1024;
  #pragma unroll
  for (int m = 0; m < 2; ++m) {
    const float* __restrict__ U = m ? U_f : U_tau;
    const float* __restrict__ b = m ? b_f : b_tau;
    #pragma unroll
    for (int hh = 0; hh < 2; ++hh) {
      const int h = tid + hh * 256;
      const float4* __restrict__ Ur = (const float4*)(U + (size_t)h * NIN);
      float acc = 0.f;
      #pragma unroll 8
      for (int k = 0; k < NIN / 4; ++k) {
        float4 u = Ur[k];
        acc = fmaf(u.x, Ish[4*k+0], acc);
        acc = fmaf(u.y, Ish[4*k+1], acc);
        acc = fmaf(u.z, Ish[4*k+2], acc);
        acc = fmaf(u.w, Ish[4*k+3], acc);
      }
      go[m * 512 + h] = acc + b[h];
    }
  }
}

// The round-3-proven scan body (dense packed words, parity ping-pong, two
// barriers, pre[] funnel, wave-0 coalesced release). FAST swaps only the
// exchange primitives: release=global_atomic_swap (L2 point), poll=sc0 load
// throttled by s_sleep(1).
template<bool FAST>
__device__ __forceinline__ void scan_loop(int rank, int tid,
    const float* __restrict__ x0, const float* __restrict__ t_save,
    const float* __restrict__ W_tau, const float* __restrict__ tau0,
    const float* __restrict__ W_f,  const float* __restrict__ gu,
    unsigned long long* xslot, float* __restrict__ out,
    float* xsp, float* pre)
{
  const int row  = tid >> 4;    // 0..63
  const int seg  = tid & 15;    // 0..15, 32 columns each
  const int base = rank * SLICE;

  const float* wrow = ((row < SLICE)
      ? (W_tau + (size_t)(base + row) * HID)
      : (W_f   + (size_t)(base + row - SLICE) * HID)) + seg * 32;

  float4 w4[8];
  #pragma unroll
  for (int t = 0; t < 8; ++t) w4[t] = ((const float4*)wrow)[t];

  float y0 = 0.f, k1 = 0.f, k2 = 0.f, k3 = 0.f, curx = 0.f, tz = 0.f;
  if (tid < SLICE) {
    y0   = x0[base + tid];
    curx = y0;
    tz   = tau0[base + tid];
    out[base + tid] = y0;              // out[0] = x0
  }

  for (int n = 0; n < NSTEP; ++n) {
    const float t0 = t_save[n], t1 = t_save[n + 1];
    const float dt = t1 - t0;
    #pragma unroll
    for (int s = 0; s < 4; ++s) {
      const int e = (n << 2) + s;

      // gu loads issued first: latency hides under the poll below
      float gt = 0.f, gf = 0.f;
      if (tid < SLICE) {
        const float* g = gu + (size_t)e * 1024 + base + tid;
        gt = g[0];
        gf = g[512];
      }

      // ---- acquire x_e: spin on packed (tag,value) words, fill LDS ----
      if (tid < HID) {
        float v;
        if (e == 0) {
          v = x0[tid];
        } else {
          unsigned long long* src = xslot + (size_t)(e & 1) * HID + tid;
          unsigned long long pk;
          if (FAST) {
            for (;;) {
              pk = sc0_load64(src);
              if ((unsigned)(pk >> 32) == (unsigned)e) break;
              __builtin_amdgcn_s_sleep(1);     // throttle: never starve the swap
            }
          } else {
            do {
              pk = __hip_atomic_load(src, __ATOMIC_RELAXED, __HIP_MEMORY_SCOPE_AGENT);
            } while ((unsigned)(pk >> 32) != (unsigned)e);
          }
          v = __uint_as_float((unsigned)pk);
        }
        xsp[(tid >> 5) * 36 + (tid & 31)] = v;
      }
      __syncthreads();

      // ---- matvec: 32 MACs/thread from VGPR weights + LDS x ----
      float acc = 0.f;
      #pragma unroll
      for (int t = 0; t < 8; ++t) {
        const float4 xv = *reinterpret_cast<const float4*>(&xsp[seg * 36 + 4 * t]);
        acc = fmaf(w4[t].x, xv.x, acc);
        acc = fmaf(w4[t].y, xv.y, acc);
        acc = fmaf(w4[t].z, xv.z, acc);
        acc = fmaf(w4[t].w, xv.w, acc);
      }
      acc += __shfl_xor(acc, 1);
      acc += __shfl_xor(acc, 2);
      acc += __shfl_xor(acc, 4);
      acc += __shfl_xor(acc, 8);
      if ((tid & 15) == 0) pre[row] = acc;
      __syncthreads();

      // ---- elementwise + RK4; wave-0 coalesced release (r3/r8-proven best) ----
      if (tid < SLICE) {
        const float zt  = pre[tid] + gt;
        const float zf  = pre[SLICE + tid] + gf;
        const float ez  = __expf(-fabsf(zt));
        const float sp  = fmaxf(zt, 0.f) + __logf(1.f + ez);
        const float tau = tz + sp;
        const float ef  = __expf(-2.f * fabsf(zf));
        const float th  = (1.f - ef) / (1.f + ef);
        const float f   = (zf >= 0.f) ? th : -th;
        const float d   = f - curx / tau;
        float xnew;
        if      (s == 0) { k1 = d; xnew = y0 + dt * k1 * (1.0f/3.0f); }
        else if (s == 1) { k2 = d; xnew = y0 + dt * (k2 - k1 * (1.0f/3.0f)); }
        else if (s == 2) { k3 = d; xnew = y0 + dt * (k1 - k2 + k3); }
        else             { xnew = y0 + (k1 + 3.0f * (k2 + k3) + d) * dt * 0.125f; y0 = xnew; }
        curx = xnew;
        const unsigned long long pk =
            ((unsigned long long)(unsigned)(e + 1) << 32) |
            (unsigned long long)__float_as_uint(xnew);
        unsigned long long* dst = xslot + (size_t)((e + 1) & 1) * HID + base + tid;
        if (FAST) l2_swap64(dst, pk);
        else __hip_atomic_store(dst, pk, __ATOMIC_RELAXED, __HIP_MEMORY_SCOPE_AGENT);
        if (s == 3) out[(size_t)(n + 1) * HID + base + tid] = xnew;
      }
    }
  }
}

// ctl[0..7]=per-XCD tickets [8]=winner(0 / xcd+1 / 9=fallback) [9]=ack
// [10]=okc [11]=mode [12]=global ticket [13]=generation. pword = probe word.
__global__ void __launch_bounds__(NTH, 1)
ltc_main(const float* __restrict__ x0, const float* __restrict__ t_save,
         const float* __restrict__ W_tau, const float* __restrict__ tau0,
         const float* __restrict__ W_f,  const float* __restrict__ gu,
         unsigned long long* xslot, unsigned* ctl, unsigned* pword,
         float* __restrict__ out)
{
  __shared__ float xsp[16 * 36];
  __shared__ float pre[64];
  __shared__ int sh_rank, sh_mode;
  const int tid = threadIdx.x;

  if (tid == 0) {
    // ---- bounded XCD election (r7-proven; fallback = first-16 global ticket) ----
    const int xcd = __builtin_amdgcn_s_getreg(6164) & 7;   // hwreg(HW_REG_XCC_ID,0,4)
    const int tk  = (int)ag_add(&ctl[xcd], 1u);
    const int gtk = (int)ag_add(&ctl[12], 1u);
    if (tk == NWG - 1) ag_cas(&ctl[8], 0u, (unsigned)(xcd + 1));
    unsigned w = 0;
    for (int it = 0; it < (1 << 20) && !(w = ag_load(&ctl[8])); ++it)
      __builtin_amdgcn_s_sleep(1);
    if (!w) { ag_cas(&ctl[8], 0u, 9u); w = ag_load(&ctl[8]); }
    int rank = -1;
    if (w == 9u) { if (gtk < NWG) rank = gtk; }
    else if ((int)(w - 1) == xcd && tk < NWG) rank = tk;

    int mode = 0;
    if (rank >= 0) {
      // ---- warm-line 3-generation probe of the EXACT FAST pair:
      //      put = l2_swap32, observe = sc0_load32. All spins bounded. ----
      int myok = 1;
      for (unsigned g = 1; g <= 3; ++g) {
        if (rank == 0) { l2_swap32(pword, g); ag_store(&ctl[13], g); }
        else {
          unsigned m = 0;
          for (int it = 0; it < (1 << 20) && (m = ag_load(&ctl[13])) < g; ++it)
            __builtin_amdgcn_s_sleep(1);
          int ok = 0;
          if (m >= g)
            for (int it = 0; it < (1 << 16); ++it)
              if (sc0_load32(pword) == g) { ok = 1; break; }
          myok &= ok;
        }
        ag_add(&ctl[9], 1u);
        if (rank == 0)
          while (ag_load(&ctl[9]) < 16u * g) __builtin_amdgcn_s_sleep(1);
      }
      ag_add(&ctl[10], (unsigned)myok);
      ag_add(&ctl[9], 1u);
      if (rank == 0) {
        while (ag_load(&ctl[9]) < 64u) __builtin_amdgcn_s_sleep(1);
        ag_store(&ctl[11], ag_load(&ctl[10]) == (unsigned)NWG ? 2u : 1u);
      }
      unsigned md;
      while (!(md = ag_load(&ctl[11]))) __builtin_amdgcn_s_sleep(1);
      mode = (int)md;
    }
    sh_rank = rank;
    sh_mode = mode;
  }
  __syncthreads();
  const int rank = sh_rank;
  if (rank < 0) return;                       // non-participants exit

  if (sh_mode == 2)
    scan_loop<true >(rank, tid, x0, t_save, W_tau, tau0, W_f, gu, xslot, out, xsp, pre);
  else
    scan_loop<false>(rank, tid, x0, t_save, W_tau, tau0, W_f, gu, xslot, out, xsp, pre);
}

extern "C" void kernel_launch(void* const* d_in, const int* in_sizes, int n_in,
                              void* d_out, int out_size, void* d_ws, size_t ws_size,
                              hipStream_t stream) {
  const float* x0     = (const float*)d_in[0];
  const float* I_seq  = (const float*)d_in[1];
  const float* t_save = (const float*)d_in[2];
  const float* W_tau  = (const float*)d_in[3];
  const float* U_tau  = (const float*)d_in[4];
  const float* b_tau  = (const float*)d_in[5];
  const float* tau0   = (const float*)d_in[6];
  const float* W_f    = (const float*)d_in[7];
  const float* U_f    = (const float*)d_in[8];
  const float* b_f    = (const float*)d_in[9];
  float* out = (float*)d_out;

  char* ws = (char*)d_ws;
  unsigned* ctl   = (unsigned*)ws;                               // [0,2048)
  unsigned* pword = (unsigned*)(ws + 2048);                      // own line
  unsigned long long* xslot = (unsigned long long*)(ws + 4096);  // [2][512] dense = 8KB
  float* gu = (float*)(ws + 16384);                              // NEVAL*1024 floats (~16.8MB)

  hipMemsetAsync(ctl, 0, 4096, stream);                          // ctl + pword
  hipMemsetAsync(xslot, 0, 2 * HID * sizeof(unsigned long long), stream);
  gu_kernel<<<NEVAL, 256, 0, stream>>>(I_seq, t_save, U_tau, b_tau, U_f, b_f, gu);

  void* args[] = { (void*)&x0, (void*)&t_save, (void*)&W_tau, (void*)&tau0, (void*)&W_f,
                   (void*)&gu, (void*)&xslot, (void*)&ctl, (void*)&pword, (void*)&out };
  hipLaunchCooperativeKernel((const void*)ltc_main, dim3(NLAUNCH), dim3(NTH),
                             args, 0, stream);
}

// Round 10
// 7074.699 us; speedup vs baseline: 2.0444x; 2.0444x over previous
//
#include <hip/hip_runtime.h>
#include <math.h>

#define HID    512
#define NIN    256
#define TIN    4096
#define NSTEP  1023
#define NEVAL  (NSTEP*4)
#define NWG    8
#define SLICE  64          // state elements owned per WG
#define NTH    1024

// searchsorted(linspace(0,1,4096), t, side='left') clipped to [0, 4095]
__device__ __forceinline__ int zoh_index(float t) {
  const float delta = 1.0f / 4095.0f;
  int lo = 0, hi = TIN;
  while (lo < hi) {
    int mid = (lo + hi) >> 1;
    float g = (float)mid * delta;
    if (g < t) lo = mid + 1; else hi = mid;
  }
  return lo > TIN - 1 ? TIN - 1 : lo;
}

// Round-3-proven gu precompute: gu[e][0:512]=U_tau@I+b_tau, gu[e][512:1024]=U_f@I+b_f
__global__ void __launch_bounds__(256)
gu_kernel(const float* __restrict__ I_seq, const float* __restrict__ t_save,
          const float* __restrict__ U_tau, const float* __restrict__ b_tau,
          const float* __restrict__ U_f,   const float* __restrict__ b_f,
          float* __restrict__ gu)
{
  __shared__ float Ish[NIN];
  const int e = blockIdx.x;
  const int tid = threadIdx.x;
  const int n = e >> 2, s = e & 3;
  const float t0 = t_save[n], t1 = t_save[n + 1];
  const float dt = t1 - t0;
  const float third = 1.0f / 3.0f;
  float t;
  if      (s == 0) t = t0;
  else if (s == 1) t = t0 + dt * third;
  else if (s == 2) t = t0 + (dt * 2.0f) * third;
  else             t = t1;
  const int idx = zoh_index(t);
  Ish[tid] = I_seq[idx * NIN + tid];
  __syncthreads();
  float* go = gu + (size_t)e * 1024;
  #pragma unroll
  for (int m = 0; m < 2; ++m) {
    const float* __restrict__ U = m ? U_f : U_tau;
    const float* __restrict__ b = m ? b_f : b_tau;
    #pragma unroll
    for (int hh = 0; hh < 2; ++hh) {
      const int h = tid + hh * 256;
      const float4* __restrict__ Ur = (const float4*)(U + (size_t)h * NIN);
      float acc = 0.f;
      #pragma unroll 8
      for (int k = 0; k < NIN / 4; ++k) {
        float4 u = Ur[k];
        acc = fmaf(u.x, Ish[4*k+0], acc);
        acc = fmaf(u.y, Ish[4*k+1], acc);
        acc = fmaf(u.z, Ish[4*k+2], acc);
        acc = fmaf(u.w, Ish[4*k+3], acc);
      }
      go[m * 512 + h] = acc + b[h];
    }
  }
}

// Persistent cooperative scan, 8 WGs x 1024 threads.
// Exchange: r3-PROVEN dense packed (tag<<32 | bits) words, agent-scope relaxed
// atomics at the LLC, parity ping-pong, pure-spin poll, single xsp buffer with
// two barriers, wave-coalesced funnel+release. Changes vs r3 (all local):
//  - NWG 8 (SLICE 64): half the producers (less burst skew), half the pollers,
//    3-level reduce, 64-lane coalesced release, full-wave producer/elementwise.
//  - dual-phase poll: threads 512..1023 poll the same words phase-shifted;
//    first detector fills LDS (same-value LDS write race is benign).
//  - rcp for the two divides; out[] store after the release store.
// Thread map: row = tid>>3 (0..127; <64 tau, >=64 f), seg = tid&7 (64 cols each).
__global__ void __launch_bounds__(NTH, 1)
ltc_main(const float* __restrict__ x0, const float* __restrict__ t_save,
         const float* __restrict__ W_tau, const float* __restrict__ tau0,
         const float* __restrict__ W_f,
         const float* __restrict__ gu,
         unsigned long long* xslot,          // [2][512] packed (tag, value)
         float* __restrict__ out)
{
  const int wg   = blockIdx.x;
  const int tid  = threadIdx.x;
  const int row  = tid >> 3;    // 0..127
  const int seg  = tid & 7;     // 0..7, 64 columns each
  const int base = wg * SLICE;

  const float* wrow = ((row < SLICE)
      ? (W_tau + (size_t)(base + row) * HID)
      : (W_f   + (size_t)(base + row - SLICE) * HID)) + seg * 64;

  float4 w4[16];
  #pragma unroll
  for (int t = 0; t < 16; ++t) w4[t] = ((const float4*)wrow)[t];

  __shared__ float xsp[8 * 68];    // [seg][64] padded to 68 -> conflict-free
  __shared__ float pre[128];

  float y0 = 0.f, k1 = 0.f, k2 = 0.f, k3 = 0.f, curx = 0.f, tz = 0.f;
  if (tid < SLICE) {
    y0   = x0[base + tid];
    curx = y0;
    tz   = tau0[base + tid];
    out[base + tid] = y0;            // out[0] = x0
  }

  for (int n = 0; n < NSTEP; ++n) {
    const float t0 = t_save[n], t1 = t_save[n + 1];
    const float dt = t1 - t0;
    #pragma unroll
    for (int s = 0; s < 4; ++s) {
      const int e = (n << 2) + s;

      // gu loads issued first: latency hides under the poll below
      float gt = 0.f, gf = 0.f;
      if (tid < SLICE) {
        const float* g = gu + (size_t)e * 1024 + base + tid;
        gt = g[0];
        gf = g[512];
      }

      // ---- acquire x_e: ALL 1024 threads poll (two phase-shifted pollers
      //      per word); first detector fills LDS ----
      {
        const int i = tid & 511;
        float v;
        if (e == 0) {
          v = x0[i];
        } else {
          const unsigned long long* src = xslot + (size_t)(e & 1) * HID + i;
          unsigned long long pk;
          do {
            pk = __hip_atomic_load(src, __ATOMIC_RELAXED, __HIP_MEMORY_SCOPE_AGENT);
          } while ((unsigned)(pk >> 32) != (unsigned)e);
          v = __uint_as_float((unsigned)pk);
        }
        xsp[(i >> 6) * 68 + (i & 63)] = v;
      }
      __syncthreads();

      // ---- matvec: 64 MACs/thread from VGPR weights + LDS x (broadcast reads) ----
      const float* xs = &xsp[seg * 68];
      float acc = 0.f;
      #pragma unroll
      for (int t = 0; t < 16; ++t) {
        const float4 xv = ((const float4*)xs)[t];
        acc = fmaf(w4[t].x, xv.x, acc);
        acc = fmaf(w4[t].y, xv.y, acc);
        acc = fmaf(w4[t].z, xv.z, acc);
        acc = fmaf(w4[t].w, xv.w, acc);
      }
      acc += __shfl_xor(acc, 1);
      acc += __shfl_xor(acc, 2);
      acc += __shfl_xor(acc, 4);
      if (seg == 0) pre[row] = acc;
      __syncthreads();

      // ---- elementwise + RK4 on one full wave; packed store IS the release ----
      if (tid < SLICE) {
        const float zt  = pre[tid] + gt;
        const float zf  = pre[SLICE + tid] + gf;
        const float ez  = __expf(-fabsf(zt));
        const float sp  = fmaxf(zt, 0.f) + __logf(1.f + ez);
        const float tau = tz + sp;
        const float ef  = __expf(-2.f * fabsf(zf));
        const float th  = (1.f - ef) * __builtin_amdgcn_rcpf(1.f + ef);
        const float f   = (zf >= 0.f) ? th : -th;
        const float d   = f - curx * __builtin_amdgcn_rcpf(tau);
        float xnew;
        if      (s == 0) { k1 = d; xnew = y0 + dt * k1 * (1.0f/3.0f); }
        else if (s == 1) { k2 = d; xnew = y0 + dt * (k2 - k1 * (1.0f/3.0f)); }
        else if (s == 2) { k3 = d; xnew = y0 + dt * (k1 - k2 + k3); }
        else             { xnew = y0 + (k1 + 3.0f * (k2 + k3) + d) * dt * 0.125f; y0 = xnew; }
        curx = xnew;
        const unsigned long long pk =
            ((unsigned long long)(unsigned)(e + 1) << 32) |
            (unsigned long long)__float_as_uint(xnew);
        __hip_atomic_store(xslot + (size_t)((e + 1) & 1) * HID + base + tid, pk,
                           __ATOMIC_RELAXED, __HIP_MEMORY_SCOPE_AGENT);
        if (s == 3) out[(size_t)(n + 1) * HID + base + tid] = xnew;  // after release
      }
      // no trailing barrier: all threads' matvec reads completed before
      // barrier 2, so the next eval's LDS fill cannot race them (r3-proven)
    }
  }
}

extern "C" void kernel_launch(void* const* d_in, const int* in_sizes, int n_in,
                              void* d_out, int out_size, void* d_ws, size_t ws_size,
                              hipStream_t stream) {
  const float* x0     = (const float*)d_in[0];
  const float* I_seq  = (const float*)d_in[1];
  const float* t_save = (const float*)d_in[2];
  const float* W_tau  = (const float*)d_in[3];
  const float* U_tau  = (const float*)d_in[4];
  const float* b_tau  = (const float*)d_in[5];
  const float* tau0   = (const float*)d_in[6];
  const float* W_f    = (const float*)d_in[7];
  const float* U_f    = (const float*)d_in[8];
  const float* b_f    = (const float*)d_in[9];
  float* out = (float*)d_out;

  char* ws = (char*)d_ws;
  unsigned long long* xslot = (unsigned long long*)(ws + 1024);  // [2][512] = 8KB
  float* gu = (float*)(ws + 16384);                              // NEVAL*1024 floats (~16.8MB)

  // zero tags every call -> replay-safe, first-call-safe (tag 0 never matches)
  hipMemsetAsync(xslot, 0, 2 * HID * sizeof(unsigned long long), stream);
  gu_kernel<<<NEVAL, 256, 0, stream>>>(I_seq, t_save, U_tau, b_tau, U_f, b_f, gu);

  void* args[] = { (void*)&x0, (void*)&t_save, (void*)&W_tau, (void*)&tau0, (void*)&W_f,
                   (void*)&gu, (void*)&xslot, (void*)&out };
  hipLaunchCooperativeKernel((const void*)ltc_main, dim3(NWG), dim3(NTH),
                             args, 0, stream);
}

// Round 11
// 7052.410 us; speedup vs baseline: 2.0509x; 1.0032x over previous
//
#include <hip/hip_runtime.h>
#include <math.h>

#define HID    512
#define NIN    256
#define TIN    4096
#define NSTEP  1023
#define NEVAL  (NSTEP*4)
#define NWG    16
#define SLICE  32          // state elements owned per WG
#define NTH    1024
#define ET     16          // evals per gu2 block

// searchsorted(linspace(0,1,4096), t, side='left') clipped to [0, 4095]
__device__ __forceinline__ int zoh_index(float t) {
  const float delta = 1.0f / 4095.0f;
  int lo = 0, hi = TIN;
  while (lo < hi) {
    int mid = (lo + hi) >> 1;
    float g = (float)mid * delta;
    if (g < t) lo = mid + 1; else hi = mid;
  }
  return lo > TIN - 1 ? TIN - 1 : lo;
}

// Tiled gu precompute (r5 retry, spill-free): block (et, rb) = 16 evals x 256 rows.
// acc[16] + u[16] + misc ~= 60 VGPR. I-tile (16x256 f32 = 16KB) staged in LDS.
// gu[e][0:512] = U_tau @ I(t_e) + b_tau ; gu[e][512:1024] = U_f @ I(t_e) + b_f.
__global__ void __launch_bounds__(256)
gu2_kernel(const float* __restrict__ I_seq, const float* __restrict__ t_save,
           const float* __restrict__ U_tau, const float* __restrict__ b_tau,
           const float* __restrict__ U_f,   const float* __restrict__ b_f,
           float* __restrict__ gu)
{
  __shared__ float Ild[ET][NIN];
  __shared__ int idxs[ET];
  const int tid = threadIdx.x;
  const int e0 = blockIdx.x * ET;
  const int rb = blockIdx.y;                  // 0..3 -> rows [256rb, +256)

  if (tid < ET) {
    const int e = e0 + tid;
    const int ec = e < NEVAL ? e : (NEVAL - 1);
    const int n = ec >> 2, s = ec & 3;
    const float t0 = t_save[n], t1 = t_save[n + 1];
    const float dt = t1 - t0;
    const float third = 1.0f / 3.0f;
    float t;
    if      (s == 0) t = t0;
    else if (s == 1) t = t0 + dt * third;
    else if (s == 2) t = t0 + (dt * 2.0f) * third;
    else             t = t1;
    idxs[tid] = zoh_index(t);
  }
  __syncthreads();
  #pragma unroll
  for (int q = 0; q < 4; ++q) {               // 1024 float4 slots = 16 evals x 64
    const int li = q * 256 + tid;
    const int ee = li >> 6, c4 = li & 63;
    ((float4*)&Ild[ee][0])[c4] = ((const float4*)(I_seq + (size_t)idxs[ee] * NIN))[c4];
  }
  __syncthreads();

  const int row = rb * 256 + tid;             // 0..1023 stacked [U_tau; U_f]
  const float* Urow = (row < HID) ? (U_tau + (size_t)row * NIN)
                                  : (U_f + (size_t)(row - HID) * NIN);
  const float bb = (row < HID) ? b_tau[row] : b_f[row - HID];
  const float4* Uv = (const float4*)Urow;

  float acc[ET];
  #pragma unroll
  for (int k = 0; k < ET; ++k) acc[k] = 0.f;

  for (int c = 0; c < NIN / 4; c += 4) {      // 16 outer iters
    const float4 u0 = Uv[c + 0], u1 = Uv[c + 1], u2 = Uv[c + 2], u3 = Uv[c + 3];
    #pragma unroll
    for (int k = 0; k < ET; ++k) {
      const float4* iv = (const float4*)&Ild[k][0];
      const float4 x0 = iv[c + 0], x1 = iv[c + 1], x2 = iv[c + 2], x3 = iv[c + 3];
      float a = acc[k];
      a = fmaf(u0.x, x0.x, a); a = fmaf(u0.y, x0.y, a);
      a = fmaf(u0.z, x0.z, a); a = fmaf(u0.w, x0.w, a);
      a = fmaf(u1.x, x1.x, a); a = fmaf(u1.y, x1.y, a);
      a = fmaf(u1.z, x1.z, a); a = fmaf(u1.w, x1.w, a);
      a = fmaf(u2.x, x2.x, a); a = fmaf(u2.y, x2.y, a);
      a = fmaf(u2.z, x2.z, a); a = fmaf(u2.w, x2.w, a);
      a = fmaf(u3.x, x3.x, a); a = fmaf(u3.y, x3.y, a);
      a = fmaf(u3.z, x3.z, a); a = fmaf(u3.w, x3.w, a);
      acc[k] = a;
    }
  }
  #pragma unroll
  for (int k = 0; k < ET; ++k) {
    const int e = e0 + k;
    if (e < NEVAL) gu[(size_t)e * 1024 + row] = acc[k] + bb;
  }
}

// Pipelined 2-alias poll: two loads in flight (vmcnt(1) waits), sampling each
// address once per full latency -> combined sampling at ~latency/2. sc1 = the
// cache policy agent-scope atomic loads lower to on gfx94x (LLC point).
// BOUNDED: after 1024 pipelined iterations, fall back to the rounds-2-10-proven
// __hip_atomic_load spin -> worst case slow, never a hang.
__device__ __forceinline__ unsigned long long poll2(
    const unsigned long long* pa, const unsigned long long* pb, unsigned tag) {
  unsigned long long va, vb;
  asm volatile("global_load_dwordx2 %0, %1, off sc1" : "=&v"(va) : "v"(pa) : "memory");
  asm volatile("global_load_dwordx2 %0, %1, off sc1" : "=&v"(vb) : "v"(pb) : "memory");
  #pragma unroll 1
  for (int it = 0; it < 1024; ++it) {
    asm volatile("s_waitcnt vmcnt(1)" ::: "memory");
    __builtin_amdgcn_sched_barrier(0);
    if ((unsigned)(va >> 32) == tag) {
      asm volatile("s_waitcnt vmcnt(0)" ::: "memory");   // drain vb's load
      return va;
    }
    asm volatile("global_load_dwordx2 %0, %1, off sc1" : "=&v"(va) : "v"(pa) : "memory");
    asm volatile("s_waitcnt vmcnt(1)" ::: "memory");
    __builtin_amdgcn_sched_barrier(0);
    if ((unsigned)(vb >> 32) == tag) {
      asm volatile("s_waitcnt vmcnt(0)" ::: "memory");
      return vb;
    }
    asm volatile("global_load_dwordx2 %0, %1, off sc1" : "=&v"(vb) : "v"(pb) : "memory");
  }
  asm volatile("s_waitcnt vmcnt(0)" ::: "memory");
  unsigned long long pk;
  do {
    pk = __hip_atomic_load(pa, __ATOMIC_RELAXED, __HIP_MEMORY_SCOPE_AGENT);
  } while ((unsigned)(pk >> 32) != tag);
  return pk;
}

// Persistent cooperative scan: EXACT round-3 structure (16 WGs x 1024, dense
// packed words, parity ping-pong, single xsp + two barriers, pre[] funnel,
// wave-0 coalesced release). Only the poll (pipelined 2-alias) and the release
// (dual-copy store) differ; both degrade to r3 semantics.
__global__ void __launch_bounds__(NTH, 1)
ltc_main(const float* __restrict__ x0, const float* __restrict__ t_save,
         const float* __restrict__ W_tau, const float* __restrict__ tau0,
         const float* __restrict__ W_f,
         const float* __restrict__ gu,
         unsigned long long* xslotA, unsigned long long* xslotB,
         float* __restrict__ out)
{
  const int wg   = blockIdx.x;
  const int tid  = threadIdx.x;
  const int row  = tid >> 4;    // 0..63
  const int seg  = tid & 15;    // 0..15, 32 columns each
  const int base = wg * SLICE;

  const float* wrow = ((row < SLICE)
      ? (W_tau + (size_t)(base + row) * HID)
      : (W_f   + (size_t)(base + row - SLICE) * HID)) + seg * 32;

  float4 w4[8];
  #pragma unroll
  for (int t = 0; t < 8; ++t) w4[t] = ((const float4*)wrow)[t];

  __shared__ float xsp[16 * 36];   // stride-36: <=2-way conflicts (free)
  __shared__ float pre[64];

  float y0 = 0.f, k1 = 0.f, k2 = 0.f, k3 = 0.f, curx = 0.f, tz = 0.f;
  if (tid < SLICE) {
    y0   = x0[base + tid];
    curx = y0;
    tz   = tau0[base + tid];
    out[base + tid] = y0;            // out[0] = x0
  }

  for (int n = 0; n < NSTEP; ++n) {
    const float t0 = t_save[n], t1 = t_save[n + 1];
    const float dt = t1 - t0;
    #pragma unroll
    for (int s = 0; s < 4; ++s) {
      const int e = (n << 2) + s;

      // gu loads issued first: latency hides under the poll below
      float gt = 0.f, gf = 0.f;
      if (tid < SLICE) {
        const float* g = gu + (size_t)e * 1024 + base + tid;
        gt = g[0];
        gf = g[512];
      }

      // ---- acquire x_e: pipelined 2-alias poll, fill LDS ----
      if (tid < HID) {
        float v;
        if (e == 0) {
          v = x0[tid];
        } else {
          const size_t off = (size_t)(e & 1) * HID + tid;
          const unsigned long long pk = poll2(xslotA + off, xslotB + off, (unsigned)e);
          v = __uint_as_float((unsigned)pk);
        }
        xsp[(tid >> 5) * 36 + (tid & 31)] = v;
      }
      __syncthreads();

      // ---- matvec: 32 MACs/thread from VGPR weights + LDS x ----
      float acc = 0.f;
      #pragma unroll
      for (int t = 0; t < 8; ++t) {
        const float4 xv = *reinterpret_cast<const float4*>(&xsp[seg * 36 + 4 * t]);
        acc = fmaf(w4[t].x, xv.x, acc);
        acc = fmaf(w4[t].y, xv.y, acc);
        acc = fmaf(w4[t].z, xv.z, acc);
        acc = fmaf(w4[t].w, xv.w, acc);
      }
      acc += __shfl_xor(acc, 1);
      acc += __shfl_xor(acc, 2);
      acc += __shfl_xor(acc, 4);
      acc += __shfl_xor(acc, 8);
      if ((tid & 15) == 0) pre[row] = acc;
      __syncthreads();

      // ---- elementwise + RK4; wave-0 coalesced dual release ----
      if (tid < SLICE) {
        const float zt  = pre[tid] + gt;
        const float zf  = pre[SLICE + tid] + gf;
        const float ez  = __expf(-fabsf(zt));
        const float sp  = fmaxf(zt, 0.f) + __logf(1.f + ez);
        const float tau = tz + sp;
        const float ef  = __expf(-2.f * fabsf(zf));
        const float th  = (1.f - ef) * __builtin_amdgcn_rcpf(1.f + ef);
        const float f   = (zf >= 0.f) ? th : -th;
        const float d   = f - curx * __builtin_amdgcn_rcpf(tau);
        float xnew;
        if      (s == 0) { k1 = d; xnew = y0 + dt * k1 * (1.0f/3.0f); }
        else if (s == 1) { k2 = d; xnew = y0 + dt * (k2 - k1 * (1.0f/3.0f)); }
        else if (s == 2) { k3 = d; xnew = y0 + dt * (k1 - k2 + k3); }
        else             { xnew = y0 + (k1 + 3.0f * (k2 + k3) + d) * dt * 0.125f; y0 = xnew; }
        curx = xnew;
        const unsigned long long pk =
            ((unsigned long long)(unsigned)(e + 1) << 32) |
            (unsigned long long)__float_as_uint(xnew);
        const size_t off = (size_t)((e + 1) & 1) * HID + base + tid;
        __hip_atomic_store(xslotA + off, pk, __ATOMIC_RELAXED, __HIP_MEMORY_SCOPE_AGENT);
        __hip_atomic_store(xslotB + off, pk, __ATOMIC_RELAXED, __HIP_MEMORY_SCOPE_AGENT);
        if (s == 3) out[(size_t)(n + 1) * HID + base + tid] = xnew;  // after release
      }
      // no trailing barrier: ordered by the two barriers above (r3-proven)
    }
  }
}

extern "C" void kernel_launch(void* const* d_in, const int* in_sizes, int n_in,
                              void* d_out, int out_size, void* d_ws, size_t ws_size,
                              hipStream_t stream) {
  const float* x0     = (const float*)d_in[0];
  const float* I_seq  = (const float*)d_in[1];
  const float* t_save = (const float*)d_in[2];
  const float* W_tau  = (const float*)d_in[3];
  const float* U_tau  = (const float*)d_in[4];
  const float* b_tau  = (const float*)d_in[5];
  const float* tau0   = (const float*)d_in[6];
  const float* W_f    = (const float*)d_in[7];
  const float* U_f    = (const float*)d_in[8];
  const float* b_f    = (const float*)d_in[9];
  float* out = (float*)d_out;

  char* ws = (char*)d_ws;
  unsigned long long* xslotA = (unsigned long long*)(ws + 1024);   // [2][512] = 8KB
  unsigned long long* xslotB = (unsigned long long*)(ws + 16384);  // [2][512] = 8KB
  float* gu = (float*)(ws + 65536);                                // ~16.8MB

  // zero tags every call -> replay-safe, first-call-safe (tag 0 never matches)
  hipMemsetAsync(xslotA, 0, 2 * HID * sizeof(unsigned long long), stream);
  hipMemsetAsync(xslotB, 0, 2 * HID * sizeof(unsigned long long), stream);
  gu2_kernel<<<dim3((NEVAL + ET - 1) / ET, 4), 256, 0, stream>>>(
      I_seq, t_save, U_tau, b_tau, U_f, b_f, gu);

  void* args[] = { (void*)&x0, (void*)&t_save, (void*)&W_tau, (void*)&tau0, (void*)&W_f,
                   (void*)&gu, (void*)&xslotA, (void*)&xslotB, (void*)&out };
  hipLaunchCooperativeKernel((const void*)ltc_main, dim3(NWG), dim3(NTH),
                             args, 0, stream);
}